// Round 14
// baseline (22.276 us; speedup 1.0000x reference)
//
#include <hip/hip_runtime.h>
#include <cstdint>

#define BTOT  4096
#define NBLK  683    // 2 waves/block x 3 batches/wave = 6 batches/block; 683*6=4098
#define T0    936    // simulate t in [936,1000): earlier steps are warmup (rounds 8/9)
#define NT    64
#define H1STR 68     // h1 row stride (dwords): %4==0 (b128 align), mod32=4 (bank spread)
#define WH1   4080   // per-wave h1 region = 60*H1STR dwords
#define LUTB  8160   // LUT base = 2*WH1
#define SMTOT 10720  // 8160 (h1 x2 waves) + 2560 (LUT) = 42.9 KB < 64 KB static limit

typedef float f32x4 __attribute__((ext_vector_type(4)));

// Two waves per block, 3 batches per wave. Per-wave structure identical to round 12
// (best: 20.7 us); block-level consolidation amortizes the LUT build (built once by
// 80 threads instead of per-wave by 40) and halves the dispatch count. Main mapping:
// lanes 0..59 = 3 groups x 20 neurons. Phase-1 mapping: lanes 0..47 = 3 groups x 16
// t-blocks; x read straight from global (coalesced b128). All fma orders unchanged
// since round 2 -> output bit-identical (absmax must stay exactly 117.5).
__global__ __launch_bounds__(128)
void snn_kernel(const float* __restrict__ x, const float* __restrict__ W1,
                const float* __restrict__ W2, const float* __restrict__ W3,
                float* __restrict__ out) {
  __shared__ __align__(16) float sm[SMTOT];
  float* lutf = sm + LUTB;
  const int tid  = threadIdx.x;
  const int lane = tid & 63;
  const int wv   = tid >> 6;
  const int bid  = blockIdx.x;
  const long bbase = (long)bid * 6 + wv * 3;

  // ---- phase-1 x loads: issued FIRST, consumed after the LUT build ----
  const int pg = (lane >> 4) < 3 ? (lane >> 4) : 2;  // lanes 48..63 dup group 2
  const int tb = lane & 15;
  long bbp = bbase + pg;
  if (bbp > BTOT - 1) bbp = BTOT - 1;
  const float* xbase = x + bbp * 14000 + T0;
  f32x4 xl[14];
  #pragma unroll
  for (int l = 0; l < 14; ++l)
    xl[l] = *(const f32x4*)(xbase + l * 1000 + tb * 4);  // coalesced b128

  // ---- LUT build (threads 0..79, once per block): thread (bi, q) owns one
  // 5-bit segment; w2r prescaled by 0.5 (exact); ascending-k conditional adds
  // -> entries bit-identical to all prior rounds.
  if (tid < 80) {
    const int bi = tid % 20;
    const int q  = tid / 20;
    float w2r[5];
    const float* wsrc = W2 + bi * 20 + q * 5;
    #pragma unroll
    for (int k = 0; k < 5; ++k) w2r[k] = 0.5f * wsrc[k];
    float* dst = lutf + q * 640 + bi;
    #pragma unroll
    for (int m = 0; m < 32; ++m) {
      float s = 0.f;
      if (m & 1)  s += w2r[0];
      if (m & 2)  s += w2r[1];
      if (m & 4)  s += w2r[2];
      if (m & 8)  s += w2r[3];
      if (m & 16) s += w2r[4];
      dst[m * 20] = s;
    }
  }

  // ---- phase-1: h1[g][i][t] = sum_l W1[i][l]*(0.5*x[g][l][t]) ----
  // fmaf(W1, 0.5x) == fmaf(0.5W1, x) bit-exactly; ascending-l order unchanged.
  #pragma unroll
  for (int l = 0; l < 14; ++l) xl[l] = xl[l] * 0.5f;    // exact (exponent only)

  if (lane < 48) {
    float* hdst = sm + wv * WH1 + pg * 20 * H1STR + tb * 4;
    #pragma unroll
    for (int ii = 0; ii < 20; ++ii) {
      f32x4 acc = 0.f;
      #pragma unroll
      for (int l = 0; l < 14; ++l) {
        const float w = W1[ii * 14 + l];   // wave-uniform -> s_load
        const f32x4 wv4 = w;
        acc = __builtin_elementwise_fma(wv4, xl[l], acc);  // v_pk_fma_f32
      }
      *(f32x4*)(hdst + ii * H1STR) = acc;
    }
  }

  const int  g3     = lane / 20;
  const int  g      = g3 < 3 ? g3 : 2;
  const int  i      = lane - g * 20;
  const int  i19    = i < 20 ? i : 19;
  const bool active = (g3 < 3);
  const long b      = bbase + g;
  const bool bvalid = (b < BTOT);

  float v1 = 0.f, v2 = 0.f, aacc = 0.f;
  const unsigned sh = 20u * (unsigned)g;

  __syncthreads();  // h1 (both waves) + LUT visible

  const float* h1p = sm + wv * WH1 + (g * 20 + i19) * H1STR;

  #pragma unroll 4
  for (int tc4 = 0; tc4 < NT / 4; ++tc4) {
    const f32x4 h1v = *(const f32x4*)(h1p + tc4 * 4);  // one b128 per 4 steps

    // ---- Phase A: v1 chain + ballots ----
    unsigned mk[4];
    #pragma unroll
    for (int dt = 0; dt < 4; ++dt) {
      v1 = fmaf(v1, 0.5f, h1v[dt]);   // v' = v/2 + h/2 (h pre-scaled)
      const bool sp1 = (v1 >= 5.0f);
      v1 = sp1 ? 0.f : v1;
      mk[dt] = (unsigned)(__ballot(sp1) >> sh);  // bits >19 junk; bfe masks
    }

    // ---- Phase B: all 16 LUT loads issued back-to-back ----
    float hq[16];
    #pragma unroll
    for (int dt = 0; dt < 4; ++dt) {
      #pragma unroll
      for (int q = 0; q < 4; ++q)
        hq[dt * 4 + q] = lutf[q * 640 + ((mk[dt] >> (5 * q)) & 31u) * 20 + i19];
    }

    // ---- Phase C: v2 / aacc chain ----
    #pragma unroll
    for (int dt = 0; dt < 4; ++dt) {
      const float h2 = (hq[dt * 4 + 0] + hq[dt * 4 + 1]) +
                       (hq[dt * 4 + 2] + hq[dt * 4 + 3]);  // already *0.5
      v2 = fmaf(v2, 0.5f, h2);
      const bool sp2 = (v2 >= 5.0f);
      v2 = sp2 ? 0.f : v2;
      aacc = fmaf(aacc, 0.5f, sp2 ? 0.5f : 0.f);
    }
  }

  // ---- Epilogue: out[b][k] = exp( sum_j W3[k][j] * a[j] ) ----
  __syncthreads();
  if (active) sm[wv * WH1 + g * 20 + i] = aacc;   // exchange reuses own h1 region
  __syncthreads();
  if (active && bvalid) {
    float4 ar4[5];
    #pragma unroll
    for (int p = 0; p < 5; ++p)
      ar4[p] = *(const float4*)(sm + wv * WH1 + g * 20 + p * 4);
    for (int q = 0; q < 25; ++q) {
      const int k = i + 20 * q;
      const float4* w3v = (const float4*)(W3 + k * 20);
      float acc = 0.f;
      #pragma unroll
      for (int p = 0; p < 5; ++p) {
        const float4 w4 = w3v[p];
        acc = fmaf(w4.x, ar4[p].x, acc);
        acc = fmaf(w4.y, ar4[p].y, acc);
        acc = fmaf(w4.z, ar4[p].z, acc);
        acc = fmaf(w4.w, ar4[p].w, acc);
      }
      out[b * 500 + k] = __expf(acc);
    }
  }
}

extern "C" void kernel_launch(void* const* d_in, const int* in_sizes, int n_in,
                              void* d_out, int out_size, void* d_ws, size_t ws_size,
                              hipStream_t stream) {
  const float* x  = (const float*)d_in[0];
  const float* W1 = (const float*)d_in[1];
  const float* W2 = (const float*)d_in[2];
  const float* W3 = (const float*)d_in[3];
  float* out = (float*)d_out;
  snn_kernel<<<dim3(NBLK), dim3(128), 0, stream>>>(x, W1, W2, W3, out);
}

// Round 15
// 20.724 us; speedup vs baseline: 1.0749x; 1.0749x over previous
//
#include <hip/hip_runtime.h>
#include <cstdint>

#define BTOT  4096
#define NBLK  1366   // 3 batches per wave; 5.34 blocks/CU
#define T0    936    // simulate t in [936,1000): earlier steps are warmup (rounds 8/9)
#define NT    64
#define H1STR 68     // h1 row stride (dwords): %4==0 (b128 align), mod32=4 (bank spread)
#define LUTB  4080   // LUT base (dwords) = 60*H1STR
#define SMTOT 6640   // 4080 (h1) + 2560 (LUT); epilogue exchange reuses sm[0:64)

typedef float f32x4 __attribute__((ext_vector_type(4)));

// Round-12 configuration (empirical optimum: 20.7 us). One wave per block.
// Main mapping: lanes 0..59 = 3 groups x 20 neurons. Phase-1 mapping: lanes
// 0..47 = 3 groups x 16 t-blocks (4 steps each); x read straight from global
// (coalesced). LUT[4][32][20] built VMEM-light from W2 with the 0.5 prescale
// folded in (bit-identical entries). Simple serial epilogue (R13's pipelined
// variant regressed); 2-wave blocks (R14) and 2-batch waves (R10) also regressed.
__global__ __launch_bounds__(64)
void snn_kernel(const float* __restrict__ x, const float* __restrict__ W1,
                const float* __restrict__ W2, const float* __restrict__ W3,
                float* __restrict__ out) {
  __shared__ __align__(16) float sm[SMTOT];
  float* lutf = sm + LUTB;
  const int lane = threadIdx.x;
  const int bid  = blockIdx.x;

  // ---- phase-1 x loads: issued FIRST, consumed after the LUT build ----
  const int pg = (lane >> 4) < 3 ? (lane >> 4) : 2;  // lanes 48..63 dup group 2
  const int tb = lane & 15;
  long bbp = (long)bid * 3 + pg;
  if (bbp > BTOT - 1) bbp = BTOT - 1;
  const float* xbase = x + bbp * 14000 + T0;
  f32x4 xl[14];
  #pragma unroll
  for (int l = 0; l < 14; ++l)
    xl[l] = *(const f32x4*)(xbase + l * 1000 + tb * 4);  // coalesced b128

  // ---- LUT build (lanes 0..39): lane (bi, half) owns neuron bi, q = 2*half+qr.
  // w2r prescaled by 0.5 (exact); ascending-k conditional adds -> entries
  // bit-identical to all prior rounds.
  if (lane < 40) {
    const int bi   = lane % 20;
    const int half = lane / 20;
    float w2r[10];
    const float* wsrc = W2 + bi * 20 + half * 10;
    #pragma unroll
    for (int k = 0; k < 5; ++k) {
      float2 t = *(const float2*)(wsrc + 2 * k);
      w2r[2 * k]     = 0.5f * t.x;
      w2r[2 * k + 1] = 0.5f * t.y;
    }
    float* dst = lutf + half * 1280 + bi;
    #pragma unroll
    for (int qr = 0; qr < 2; ++qr) {
      #pragma unroll
      for (int m = 0; m < 32; ++m) {
        float s = 0.f;
        if (m & 1)  s += w2r[qr * 5 + 0];
        if (m & 2)  s += w2r[qr * 5 + 1];
        if (m & 4)  s += w2r[qr * 5 + 2];
        if (m & 8)  s += w2r[qr * 5 + 3];
        if (m & 16) s += w2r[qr * 5 + 4];
        dst[qr * 640 + m * 20] = s;
      }
    }
  }

  // ---- phase-1: h1[g][i][t] = sum_l W1[i][l]*(0.5*x[g][l][t]) ----
  // fmaf(W1, 0.5x) == fmaf(0.5W1, x) bit-exactly; ascending-l order unchanged.
  #pragma unroll
  for (int l = 0; l < 14; ++l) xl[l] = xl[l] * 0.5f;    // exact (exponent only)

  if (lane < 48) {
    float* hdst = sm + pg * 20 * H1STR + tb * 4;
    #pragma unroll
    for (int ii = 0; ii < 20; ++ii) {
      f32x4 acc = 0.f;
      #pragma unroll
      for (int l = 0; l < 14; ++l) {
        const float w = W1[ii * 14 + l];   // wave-uniform -> s_load
        const f32x4 wv = w;
        acc = __builtin_elementwise_fma(wv, xl[l], acc);  // v_pk_fma_f32
      }
      *(f32x4*)(hdst + ii * H1STR) = acc;
    }
  }

  const int  g3     = lane / 20;
  const int  g      = g3 < 3 ? g3 : 2;
  const int  i      = lane - g * 20;
  const int  i19    = i < 20 ? i : 19;
  const bool active = (g3 < 3);
  const long b      = (long)bid * 3 + g;
  const bool bvalid = (b < BTOT);

  float v1 = 0.f, v2 = 0.f, aacc = 0.f;
  const unsigned sh = 20u * (unsigned)g;

  __syncthreads();  // h1 + LUT visible

  const float* h1p = sm + (g * 20 + i19) * H1STR;

  #pragma unroll 4
  for (int tc4 = 0; tc4 < NT / 4; ++tc4) {
    const f32x4 h1v = *(const f32x4*)(h1p + tc4 * 4);  // one b128 per 4 steps

    // ---- Phase A: v1 chain + ballots ----
    unsigned mk[4];
    #pragma unroll
    for (int dt = 0; dt < 4; ++dt) {
      v1 = fmaf(v1, 0.5f, h1v[dt]);   // v' = v/2 + h/2 (h pre-scaled)
      const bool sp1 = (v1 >= 5.0f);
      v1 = sp1 ? 0.f : v1;
      mk[dt] = (unsigned)(__ballot(sp1) >> sh);  // bits >19 junk; bfe masks
    }

    // ---- Phase B: all 16 LUT loads issued back-to-back ----
    float hq[16];
    #pragma unroll
    for (int dt = 0; dt < 4; ++dt) {
      #pragma unroll
      for (int q = 0; q < 4; ++q)
        hq[dt * 4 + q] = lutf[q * 640 + ((mk[dt] >> (5 * q)) & 31u) * 20 + i19];
    }

    // ---- Phase C: v2 / aacc chain ----
    #pragma unroll
    for (int dt = 0; dt < 4; ++dt) {
      const float h2 = (hq[dt * 4 + 0] + hq[dt * 4 + 1]) +
                       (hq[dt * 4 + 2] + hq[dt * 4 + 3]);  // already *0.5
      v2 = fmaf(v2, 0.5f, h2);
      const bool sp2 = (v2 >= 5.0f);
      v2 = sp2 ? 0.f : v2;
      aacc = fmaf(aacc, 0.5f, sp2 ? 0.5f : 0.f);
    }
  }

  // ---- Epilogue: out[b][k] = exp( sum_j W3[k][j] * a[j] ) ----
  __syncthreads();
  if (active) sm[g * 20 + i] = aacc;   // exchange reuses h1 region (dead)
  __syncthreads();
  if (active && bvalid) {
    float4 ar4[5];
    #pragma unroll
    for (int p = 0; p < 5; ++p)
      ar4[p] = *(const float4*)(sm + g * 20 + p * 4);
    for (int q = 0; q < 25; ++q) {
      const int k = i + 20 * q;
      const float4* w3v = (const float4*)(W3 + k * 20);
      float acc = 0.f;
      #pragma unroll
      for (int p = 0; p < 5; ++p) {
        const float4 w4 = w3v[p];
        acc = fmaf(w4.x, ar4[p].x, acc);
        acc = fmaf(w4.y, ar4[p].y, acc);
        acc = fmaf(w4.z, ar4[p].z, acc);
        acc = fmaf(w4.w, ar4[p].w, acc);
      }
      out[b * 500 + k] = __expf(acc);
    }
  }
}

extern "C" void kernel_launch(void* const* d_in, const int* in_sizes, int n_in,
                              void* d_out, int out_size, void* d_ws, size_t ws_size,
                              hipStream_t stream) {
  const float* x  = (const float*)d_in[0];
  const float* W1 = (const float*)d_in[1];
  const float* W2 = (const float*)d_in[2];
  const float* W3 = (const float*)d_in[3];
  float* out = (float*)d_out;
  snn_kernel<<<dim3(NBLK), dim3(64), 0, stream>>>(x, W1, W2, W3, out);
}